// Round 1
// baseline (134.566 us; speedup 1.0000x reference)
//
#include <hip/hip_runtime.h>
#include <hip/hip_bf16.h>

typedef __bf16 bf16;
typedef __attribute__((ext_vector_type(8))) __bf16 bf16x8;
typedef __attribute__((ext_vector_type(4))) float f32x4;
typedef __attribute__((ext_vector_type(4))) int i32x4;

#define CH 192
#define MAT (CH * CH)            // 36864
#define NF 145                   // canonical frequencies of 17x17 grid (conj symmetry)
#define FSTRIDE (2 * MAT)        // Re+Im per freq
#define NELEM (CH * CH * 9)      // 331776

// ---------------------------------------------------------------------------
// ws layout (bytes):
//   [0]       float S0  (sum of K^2)
//   [4]       float s3  (sum_w ||H3(w)||_F^2, conj-weighted)
//   [256]     KT   fp32  [a][o][tap]          1,327,104 B
//   [+KT]     bufX bf16  [f][2][a(192)][o(192)]  21,381,120 B
//   [+bufX]   bufH bf16  same                    21,381,120 B
// total ~44.1 MB
// ---------------------------------------------------------------------------

__global__ void k_zero(float* ws) {
    if (threadIdx.x < 64) ws[threadIdx.x] = 0.0f;
}

// S0 = sum K^2; KT[a][o][tap] = K[o][a][tap]   (transpose so DFT reads coalesce)
__global__ void k_prep(const float* __restrict__ K, float* __restrict__ KT,
                       float* __restrict__ S0) {
    int t = blockIdx.x * 256 + threadIdx.x;      // t = o*192 + a, 144 blocks
    float v[9];
    float ss = 0.f;
    const float* src = K + (size_t)t * 9;
#pragma unroll
    for (int i = 0; i < 9; ++i) { v[i] = src[i]; ss += v[i] * v[i]; }
    int o = t / CH, a = t % CH;
    float* dst = KT + (size_t)(a * CH + o) * 9;
#pragma unroll
    for (int i = 0; i < 9; ++i) dst[i] = v[i];
    // reduce ss over block
#pragma unroll
    for (int off = 32; off > 0; off >>= 1) ss += __shfl_down(ss, off, 64);
    __shared__ float red[4];
    int lane = threadIdx.x & 63, w = threadIdx.x >> 6;
    if (lane == 0) red[w] = ss;
    __syncthreads();
    if (threadIdx.x == 0) atomicAdd(S0, red[0] + red[1] + red[2] + red[3]);
}

// bufX[f][part][a][o] = DFT_{17x17}(K[o][a][:,:])(w_f) / f0, bf16
__global__ void k_dft(const float* __restrict__ KT, const float* __restrict__ S0,
                      bf16* __restrict__ X) {
    __shared__ float twc[17], tws[17];
    int bx = blockIdx.x;                  // 145*144 blocks
    int f = bx / 144, sub = bx % 144;
    int t = threadIdx.x;
    if (t < 17) {
        float ang = -6.283185307179586f * (float)t / 17.0f;
        twc[t] = __cosf(ang) * 0.f + cosf(ang);  // use precise cosf/sinf
        tws[t] = sinf(ang);
    }
    __syncthreads();
    int fy, fx;
    if (f < 9) { fy = 0; fx = f; }
    else { int u = f - 9; fy = 1 + u / 17; fx = u % 17; }
    int p = sub * 256 + t;                // p = a*192 + o, o fastest
    const float* src = KT + (size_t)p * 9;
    float ar = 0.f, ai = 0.f;
#pragma unroll
    for (int y = 0; y < 3; ++y)
#pragma unroll
        for (int x = 0; x < 3; ++x) {
            int ph = (fy * y + fx * x) % 17;
            float kv = src[y * 3 + x];
            ar += kv * twc[ph];
            ai += kv * tws[ph];
        }
    float f0inv = 1.0f / sqrtf(*S0);
    size_t base = (size_t)f * FSTRIDE;
    X[base + p]       = (bf16)(ar * f0inv);
    X[base + MAT + p] = (bf16)(ai * f0inv);
}

// One conj-gram round: OUT[m,n] = sum_k conj(X[m,k]) * X[n,k]  (per freq).
// Re = Xr_m.Xr_n + Xi_m.Xi_n ; Im = Xr_m.Xi_n - Xi_m.Xr_n.
// Hermitian-conj flips from round reuse cancel in Re/norms (see session notes).
// Grid: 145 freqs * 4 quadrants (96x96). Block 256 = 4 waves, wave = 48x48 cplx.
#define LDSR 72                  // 64 + 8 bf16 pad (row = 144 B -> 2-way banks, free)
#define SLAB (96 * LDSR)         // 6912 elems

template <bool WRITE, bool NORM>
__global__ __launch_bounds__(256, 2) void k_gram(const bf16* __restrict__ X,
                                                 bf16* __restrict__ Y,
                                                 float* __restrict__ s3) {
    __shared__ bf16 lds[4 * SLAB];      // Ar Ai Br Bi : 55296 B
    __shared__ float red[4];
    int bid = blockIdx.x;
    int f = bid >> 2, quad = bid & 3;
    int row0 = (quad >> 1) * 96, col0 = (quad & 1) * 96;
    const bf16* Xf = X + (size_t)f * FSTRIDE;

    int tid = threadIdx.x;
    int lane = tid & 63, w = tid >> 6;
    int wr = (w >> 1) * 48, wc = (w & 1) * 48;
    int ml = lane & 15, kq = (lane >> 4) * 8;

    f32x4 cr[3][3], ci[3][3];
#pragma unroll
    for (int i = 0; i < 3; ++i)
#pragma unroll
        for (int j = 0; j < 3; ++j) {
            cr[i][j] = f32x4{0.f, 0.f, 0.f, 0.f};
            ci[i][j] = f32x4{0.f, 0.f, 0.f, 0.f};
        }

    for (int kc = 0; kc < CH; kc += 64) {
        // stage 4 slabs (96 rows x 64 bf16) to regs, then LDS
        i32x4 v[12];
#pragma unroll
        for (int s = 0; s < 4; ++s) {
            const bf16* src = Xf + ((s & 1) ? MAT : 0)
                              + (size_t)((s < 2) ? row0 : col0) * CH + kc;
#pragma unroll
            for (int j = 0; j < 3; ++j) {
                int chunk = j * 256 + tid;
                int r = chunk >> 3, c8 = chunk & 7;
                v[s * 3 + j] = *(const i32x4*)(src + r * CH + c8 * 8);
            }
        }
        __syncthreads();   // previous compute done before LDS overwrite
#pragma unroll
        for (int s = 0; s < 4; ++s)
#pragma unroll
            for (int j = 0; j < 3; ++j) {
                int chunk = j * 256 + tid;
                int r = chunk >> 3, c8 = chunk & 7;
                *(i32x4*)&lds[s * SLAB + r * LDSR + c8 * 8] = v[s * 3 + j];
            }
        __syncthreads();

#pragma unroll
        for (int ks = 0; ks < 64; ks += 32) {
            bf16x8 ar[3], ai[3], nai[3], br[3], bi[3];
            int ko = ks + kq;
#pragma unroll
            for (int mt = 0; mt < 3; ++mt) {
                ar[mt] = *(const bf16x8*)&lds[0 * SLAB + (wr + mt * 16 + ml) * LDSR + ko];
                ai[mt] = *(const bf16x8*)&lds[1 * SLAB + (wr + mt * 16 + ml) * LDSR + ko];
                br[mt] = *(const bf16x8*)&lds[2 * SLAB + (wc + mt * 16 + ml) * LDSR + ko];
                bi[mt] = *(const bf16x8*)&lds[3 * SLAB + (wc + mt * 16 + ml) * LDSR + ko];
                i32x4 u = __builtin_bit_cast(i32x4, ai[mt]);
                u ^= 0x80008000;   // negate 8 bf16 (sign bits)
                nai[mt] = __builtin_bit_cast(bf16x8, u);
            }
#pragma unroll
            for (int mt = 0; mt < 3; ++mt)
#pragma unroll
                for (int nt = 0; nt < 3; ++nt) {
                    cr[mt][nt] = __builtin_amdgcn_mfma_f32_16x16x32_bf16(ar[mt],  br[nt], cr[mt][nt], 0, 0, 0);
                    cr[mt][nt] = __builtin_amdgcn_mfma_f32_16x16x32_bf16(ai[mt],  bi[nt], cr[mt][nt], 0, 0, 0);
                    ci[mt][nt] = __builtin_amdgcn_mfma_f32_16x16x32_bf16(ar[mt],  bi[nt], ci[mt][nt], 0, 0, 0);
                    ci[mt][nt] = __builtin_amdgcn_mfma_f32_16x16x32_bf16(nai[mt], br[nt], ci[mt][nt], 0, 0, 0);
                }
        }
    }

    if (WRITE) {
        bf16* Yf = Y + (size_t)f * FSTRIDE;
        int rbase = row0 + wr + (lane >> 4) * 4;
        int cbase = col0 + wc + ml;
#pragma unroll
        for (int mt = 0; mt < 3; ++mt)
#pragma unroll
            for (int nt = 0; nt < 3; ++nt)
#pragma unroll
                for (int r = 0; r < 4; ++r) {
                    int row = rbase + mt * 16 + r;
                    int col = cbase + nt * 16;
                    Yf[(size_t)row * CH + col]       = (bf16)cr[mt][nt][r];
                    Yf[MAT + (size_t)row * CH + col] = (bf16)ci[mt][nt][r];
                }
    }
    if (NORM) {
        float loc = 0.f;
#pragma unroll
        for (int mt = 0; mt < 3; ++mt)
#pragma unroll
            for (int nt = 0; nt < 3; ++nt)
#pragma unroll
                for (int r = 0; r < 4; ++r)
                    loc += cr[mt][nt][r] * cr[mt][nt][r] + ci[mt][nt][r] * ci[mt][nt][r];
#pragma unroll
        for (int off = 32; off > 0; off >>= 1) loc += __shfl_down(loc, off, 64);
        if (lane == 0) red[w] = loc;
        __syncthreads();
        if (tid == 0) {
            float wgt = (f == 0) ? 1.0f : 2.0f;   // conj-pair weight
            atomicAdd(s3, wgt * (red[0] + red[1] + red[2] + red[3]));
        }
    }
}

// sigma = f0 * (s3/289)^(1/16);  out = K / sigma
__global__ void k_scale(const float* __restrict__ K, float* __restrict__ out,
                        const float* __restrict__ S0, const float* __restrict__ s3) {
    float sig = sqrtf(*S0) * exp2f(log2f((*s3) * (1.0f / 289.0f)) * 0.0625f);
    float inv = 1.0f / sig;
    int i = (blockIdx.x * 256 + threadIdx.x) * 4;   // 324 blocks exact
    f32x4 v = *(const f32x4*)(K + i);
    v *= inv;
    *(f32x4*)(out + i) = v;
}

extern "C" void kernel_launch(void* const* d_in, const int* in_sizes, int n_in,
                              void* d_out, int out_size, void* d_ws, size_t ws_size,
                              hipStream_t stream) {
    const float* K = (const float*)d_in[0];
    float* out = (float*)d_out;
    char* ws = (char*)d_ws;
    float* S0 = (float*)ws;
    float* s3 = (float*)ws + 1;
    float* KT = (float*)(ws + 256);
    bf16* bufX = (bf16*)(ws + 256 + 1327104);
    bf16* bufH = bufX + (size_t)NF * FSTRIDE;

    k_zero<<<1, 64, 0, stream>>>((float*)ws);
    k_prep<<<MAT / 256, 256, 0, stream>>>(K, KT, S0);
    k_dft<<<NF * 144, 256, 0, stream>>>(KT, S0, bufX);
    k_gram<true,  false><<<NF * 4, 256, 0, stream>>>(bufX, bufH, nullptr);  // H1
    k_gram<true,  false><<<NF * 4, 256, 0, stream>>>(bufH, bufX, nullptr);  // H2 (X dead)
    k_gram<false, true ><<<NF * 4, 256, 0, stream>>>(bufX, nullptr, s3);    // ||H3||^2
    k_scale<<<NELEM / 1024, 256, 0, stream>>>(K, out, S0, s3);
}

// Round 2
// 122.193 us; speedup vs baseline: 1.1013x; 1.1013x over previous
//
#include <hip/hip_runtime.h>
#include <hip/hip_bf16.h>

typedef __bf16 bf16;
typedef __attribute__((ext_vector_type(8))) __bf16 bf16x8;
typedef __attribute__((ext_vector_type(4))) float f32x4;
typedef __attribute__((ext_vector_type(4))) int i32x4;

#define CH 192
#define MAT (CH * CH)            // 36864
#define NF 145                   // canonical frequencies of 17x17 grid (conj symmetry)
#define FSTRIDE (2 * MAT)        // Re+Im per freq
#define NELEM (CH * CH * 9)      // 331776
#define XSCALE 9.765625e-4f      // 2^-10, exact; sigma = 1024*(s3/289)^(1/16)

// ---------------------------------------------------------------------------
// sigma = ||G^3(K)||_F^(1/8): full telescoping, no f0 needed (verified algebra,
// round-1 passed with the f0-variant; c=2^-10 static scale keeps fp32 range).
// ws layout: [0] float s3; [256] bufX bf16 [f][2][a][o] 21,381,120 B; bufH same.
// ---------------------------------------------------------------------------

// X[f][part][a][o] = DFT_17x17(K[o][a])(w_f) * 2^-10.  4 freqs per block.
// Reads K directly (L2-resident, 37x re-read); twiddles via v_cos/v_sin.
__global__ void k_dft(const float* __restrict__ K, bf16* __restrict__ X,
                      float* __restrict__ s3) {
    int bid = blockIdx.x;                 // 37*144 blocks
    int g = bid / 144, sub = bid % 144;
    int t = threadIdx.x;
    if (bid == 0 && t == 0) *s3 = 0.0f;   // stream-ordered: done before gram C
    int p = sub * 256 + t;                // p = a*192 + o
    int a = p / CH, o = p % CH;
    const float* src = K + (size_t)(o * CH + a) * 9;
    float kv[9];
#pragma unroll
    for (int i = 0; i < 9; ++i) kv[i] = src[i];
#pragma unroll
    for (int ff = 0; ff < 4; ++ff) {
        int f = g * 4 + ff;
        if (f < NF) {
            int fy, fx;
            if (f < 9) { fy = 0; fx = f; }
            else { int u = f - 9; fy = 1 + u / 17; fx = u % 17; }
            float ar = 0.f, ai = 0.f;
#pragma unroll
            for (int y = 0; y < 3; ++y)
#pragma unroll
                for (int x = 0; x < 3; ++x) {
                    float ang = 0.36959913571644626f * (float)(fy * y + fx * x); // 2pi/17
                    float c = __cosf(ang), s = -__sinf(ang);
                    float kvv = kv[y * 3 + x];
                    ar += kvv * c;
                    ai += kvv * s;
                }
            size_t base = (size_t)f * FSTRIDE;
            X[base + p]       = (bf16)(ar * XSCALE);
            X[base + MAT + p] = (bf16)(ai * XSCALE);
        }
    }
}

// One conj-gram round: OUT[m,n] = sum_k conj(X[m,k]) * X[n,k]  (per freq).
// Re = Xr_m.Xr_n + Xi_m.Xi_n ; Im = Xr_m.Xi_n - Xi_m.Xr_n.  Output Hermitian.
// WRITE rounds: 4 quadrants (96x96) per freq. NORM round: 3 quadrants
// (0,0),(0,96),(96,96); off-diagonal weighted 2x (Hermitian symmetry).
// Block 256 = 4 waves, wave = 48x48 complex (3x3 frags of 16x16).
#define LDSR 72                  // 64 + 8 bf16 pad (row stride 36 dwords = free 2-way)
#define SLAB (96 * LDSR)         // 6912 elems

template <bool WRITE, bool NORM>
__global__ __launch_bounds__(256, 2) void k_gram(const bf16* __restrict__ X,
                                                 bf16* __restrict__ Y,
                                                 float* __restrict__ s3) {
    __shared__ bf16 lds[4 * SLAB];      // Ar Ai Br Bi : 55296 B
    __shared__ float red[4];
    int bid = blockIdx.x;
    int f, row0, col0, wq;
    if (NORM) {
        f = bid / 3; int q = bid % 3;       // q: 0=(0,0) 1=(0,96) 2=(96,96)
        row0 = (q == 2) ? 96 : 0;
        col0 = (q >= 1) ? 96 : 0;
        wq = (q == 1) ? 2 : 1;
    } else {
        f = bid >> 2; int quad = bid & 3;
        row0 = (quad >> 1) * 96; col0 = (quad & 1) * 96;
        wq = 1;
    }
    const bf16* Xf = X + (size_t)f * FSTRIDE;

    int tid = threadIdx.x;
    int lane = tid & 63, w = tid >> 6;
    int wr = (w >> 1) * 48, wc = (w & 1) * 48;
    int ml = lane & 15, kq = (lane >> 4) * 8;

    f32x4 cr[3][3], ci[3][3];
#pragma unroll
    for (int i = 0; i < 3; ++i)
#pragma unroll
        for (int j = 0; j < 3; ++j) {
            cr[i][j] = f32x4{0.f, 0.f, 0.f, 0.f};
            ci[i][j] = f32x4{0.f, 0.f, 0.f, 0.f};
        }

    for (int kc = 0; kc < CH; kc += 64) {
        // stage 4 slabs (96 rows x 64 bf16) to regs, then LDS
        i32x4 v[12];
#pragma unroll
        for (int s = 0; s < 4; ++s) {
            const bf16* src = Xf + ((s & 1) ? MAT : 0)
                              + (size_t)((s < 2) ? row0 : col0) * CH + kc;
#pragma unroll
            for (int j = 0; j < 3; ++j) {
                int chunk = j * 256 + tid;
                int r = chunk >> 3, c8 = chunk & 7;
                v[s * 3 + j] = *(const i32x4*)(src + r * CH + c8 * 8);
            }
        }
        __syncthreads();   // previous compute done before LDS overwrite
#pragma unroll
        for (int s = 0; s < 4; ++s)
#pragma unroll
            for (int j = 0; j < 3; ++j) {
                int chunk = j * 256 + tid;
                int r = chunk >> 3, c8 = chunk & 7;
                *(i32x4*)&lds[s * SLAB + r * LDSR + c8 * 8] = v[s * 3 + j];
            }
        __syncthreads();

#pragma unroll
        for (int ks = 0; ks < 64; ks += 32) {
            bf16x8 ar[3], ai[3], nai[3], br[3], bi[3];
            int ko = ks + kq;
#pragma unroll
            for (int mt = 0; mt < 3; ++mt) {
                ar[mt] = *(const bf16x8*)&lds[0 * SLAB + (wr + mt * 16 + ml) * LDSR + ko];
                ai[mt] = *(const bf16x8*)&lds[1 * SLAB + (wr + mt * 16 + ml) * LDSR + ko];
                br[mt] = *(const bf16x8*)&lds[2 * SLAB + (wc + mt * 16 + ml) * LDSR + ko];
                bi[mt] = *(const bf16x8*)&lds[3 * SLAB + (wc + mt * 16 + ml) * LDSR + ko];
                i32x4 u = __builtin_bit_cast(i32x4, ai[mt]);
                u ^= 0x80008000;   // negate 8 bf16 (sign bits)
                nai[mt] = __builtin_bit_cast(bf16x8, u);
            }
#pragma unroll
            for (int mt = 0; mt < 3; ++mt)
#pragma unroll
                for (int nt = 0; nt < 3; ++nt) {
                    cr[mt][nt] = __builtin_amdgcn_mfma_f32_16x16x32_bf16(ar[mt],  br[nt], cr[mt][nt], 0, 0, 0);
                    cr[mt][nt] = __builtin_amdgcn_mfma_f32_16x16x32_bf16(ai[mt],  bi[nt], cr[mt][nt], 0, 0, 0);
                    ci[mt][nt] = __builtin_amdgcn_mfma_f32_16x16x32_bf16(ar[mt],  bi[nt], ci[mt][nt], 0, 0, 0);
                    ci[mt][nt] = __builtin_amdgcn_mfma_f32_16x16x32_bf16(nai[mt], br[nt], ci[mt][nt], 0, 0, 0);
                }
        }
    }

    if (WRITE) {
        bf16* Yf = Y + (size_t)f * FSTRIDE;
        int rbase = row0 + wr + (lane >> 4) * 4;
        int cbase = col0 + wc + ml;
#pragma unroll
        for (int mt = 0; mt < 3; ++mt)
#pragma unroll
            for (int nt = 0; nt < 3; ++nt)
#pragma unroll
                for (int r = 0; r < 4; ++r) {
                    int row = rbase + mt * 16 + r;
                    int col = cbase + nt * 16;
                    Yf[(size_t)row * CH + col]       = (bf16)cr[mt][nt][r];
                    Yf[MAT + (size_t)row * CH + col] = (bf16)ci[mt][nt][r];
                }
    }
    if (NORM) {
        float loc = 0.f;
#pragma unroll
        for (int mt = 0; mt < 3; ++mt)
#pragma unroll
            for (int nt = 0; nt < 3; ++nt)
#pragma unroll
                for (int r = 0; r < 4; ++r)
                    loc += cr[mt][nt][r] * cr[mt][nt][r] + ci[mt][nt][r] * ci[mt][nt][r];
#pragma unroll
        for (int off = 32; off > 0; off >>= 1) loc += __shfl_down(loc, off, 64);
        if (lane == 0) red[w] = loc;
        __syncthreads();
        if (tid == 0) {
            float base = (f == 0) ? 1.0f : 2.0f;   // conj-pair weight over freqs
            atomicAdd(s3, base * (float)wq * (red[0] + red[1] + red[2] + red[3]));
        }
    }
}

// sigma = 1024 * (s3/289)^(1/16);  out = K / sigma
__global__ void k_scale(const float* __restrict__ K, float* __restrict__ out,
                        const float* __restrict__ s3) {
    float sig = 1024.0f * exp2f(log2f((*s3) * (1.0f / 289.0f)) * 0.0625f);
    float inv = 1.0f / sig;
    int i = (blockIdx.x * 256 + threadIdx.x) * 4;   // 324 blocks exact
    f32x4 v = *(const f32x4*)(K + i);
    v *= inv;
    *(f32x4*)(out + i) = v;
}

extern "C" void kernel_launch(void* const* d_in, const int* in_sizes, int n_in,
                              void* d_out, int out_size, void* d_ws, size_t ws_size,
                              hipStream_t stream) {
    const float* K = (const float*)d_in[0];
    float* out = (float*)d_out;
    char* ws = (char*)d_ws;
    float* s3 = (float*)ws;
    bf16* bufX = (bf16*)(ws + 256);
    bf16* bufH = bufX + (size_t)NF * FSTRIDE;

    k_dft<<<37 * 144, 256, 0, stream>>>(K, bufX, s3);                       // X
    k_gram<true,  false><<<NF * 4, 256, 0, stream>>>(bufX, bufH, nullptr);  // H1
    k_gram<true,  false><<<NF * 4, 256, 0, stream>>>(bufH, bufX, nullptr);  // H2
    k_gram<false, true ><<<NF * 3, 256, 0, stream>>>(bufX, nullptr, s3);    // ||H3||^2
    k_scale<<<NELEM / 1024, 256, 0, stream>>>(K, out, s3);
}

// Round 3
// 117.261 us; speedup vs baseline: 1.1476x; 1.0421x over previous
//
#include <hip/hip_runtime.h>
#include <hip/hip_bf16.h>

typedef __bf16 bf16;
typedef __attribute__((ext_vector_type(8))) __bf16 bf16x8;
typedef __attribute__((ext_vector_type(4))) float f32x4;
typedef __attribute__((ext_vector_type(4))) int i32x4;

#define CH 192
#define MAT (CH * CH)            // 36864
#define NF 145                   // canonical frequencies of 17x17 grid (conj symmetry)
#define FSTRIDE (2 * MAT)        // Re+Im per freq
#define NELEM (CH * CH * 9)      // 331776
#define XSCALE 9.765625e-4f      // 2^-10, exact; sigma = 1024*(s3/289)^(1/16)
#define W17 0.36959913571644626f // 2*pi/17

// ---------------------------------------------------------------------------
// sigma = ||G^3(K)||_F^(1/8) via 17x17 spectral sampling (exact Parseval).
// XCD pinning: freq f is always processed by blocks with blockIdx%8 == f%8,
// so each XCD's L2 keeps its 19-freq slice (~2.8 MB) resident across kernels
// (assumes round-robin blockIdx->XCD; if not, neutral).
// ws layout: [0] float s3; [256] bufX bf16 [f][2][a][o]; bufH same (~21.4 MB ea).
// ---------------------------------------------------------------------------

// X[f][part][a][o] = DFT_17x17(K[o][a])(w_f) * 2^-10.
// 4 freqs per block, strided by 8 so all share one target XCD.
// Twiddles via complex-power recurrence: 4 transcendentals/freq (was 18).
__global__ void k_dft(const float* __restrict__ K, bf16* __restrict__ X,
                      float* __restrict__ s3) {
    int bid = blockIdx.x;                 // 8 * 5 * 144 = 5760
    int xcd = bid & 7;
    int r = bid >> 3;
    int g4 = r / 144, sub = r % 144;
    int t = threadIdx.x;
    if (bid == 0 && t == 0) *s3 = 0.0f;   // stream-ordered: done before gram C
    int p = sub * 256 + t;                // p = a*192 + o
    int a = p / CH, o = p % CH;
    const float* src = K + (size_t)(o * CH + a) * 9;
    float kv[9];
#pragma unroll
    for (int i = 0; i < 9; ++i) kv[i] = src[i];
#pragma unroll
    for (int jj = 0; jj < 4; ++jj) {
        int f = xcd + 8 * (g4 * 4 + jj);  // f % 8 == xcd
        if (f >= NF) break;               // uniform per block
        int fy, fx;
        if (f < 9) { fy = 0; fx = f; }
        else { int u = f - 9; fy = 1 + u / 17; fx = u % 17; }
        float pyi, pyr, pxi, pxr;
        __sincosf(-W17 * (float)fy, &pyi, &pyr);   // py = e^{-i*2pi*fy/17}
        __sincosf(-W17 * (float)fx, &pxi, &pxr);   // px = e^{-i*2pi*fx/17}
        float px2r = pxr * pxr - pxi * pxi, px2i = 2.f * pxr * pxi;
        float py2r = pyr * pyr - pyi * pyi, py2i = 2.f * pyr * pyi;
        // row sums s_y = kv[y][0] + kv[y][1]*px + kv[y][2]*px^2  (kv real)
        float s0r = kv[0] + kv[1] * pxr + kv[2] * px2r, s0i = kv[1] * pxi + kv[2] * px2i;
        float s1r = kv[3] + kv[4] * pxr + kv[5] * px2r, s1i = kv[4] * pxi + kv[5] * px2i;
        float s2r = kv[6] + kv[7] * pxr + kv[8] * px2r, s2i = kv[7] * pxi + kv[8] * px2i;
        // total = s0 + py*s1 + py^2*s2
        float ar = s0r + pyr * s1r - pyi * s1i + py2r * s2r - py2i * s2i;
        float ai = s0i + pyr * s1i + pyi * s1r + py2r * s2i + py2i * s2r;
        size_t base = (size_t)f * FSTRIDE;
        X[base + p]       = (bf16)(ar * XSCALE);
        X[base + MAT + p] = (bf16)(ai * XSCALE);
    }
}

// One conj-gram round: OUT[m,n] = sum_k conj(X[m,k]) * X[n,k]  (per freq).
// WRITE: 4 quadrants (96x96)/freq, grid 8*19*4. NORM: 3 Hermitian quadrants
// (0,0),(0,96),(96,96), off-diag weighted 2x, grid 8*19*3.
#define LDSR 72                  // 64 + 8 bf16 pad (row stride 36 dwords)
#define SLAB (96 * LDSR)         // 6912 elems
#define OLDSR 104                // epilogue tile stride: 208 B = 13*16 (b128-aligned)

template <bool WRITE, bool NORM>
__global__ __launch_bounds__(256, 2) void k_gram(const bf16* __restrict__ X,
                                                 bf16* __restrict__ Y,
                                                 float* __restrict__ s3) {
    __shared__ bf16 lds[4 * SLAB];      // Ar Ai Br Bi : 55296 B
    __shared__ float red[4];
    int bid = blockIdx.x;
    int xcd = bid & 7, r = bid >> 3;
    int f, row0, col0, wq;
    if (NORM) {
        int fi = r / 3, q = r % 3;          // q: 0=(0,0) 1=(0,96) 2=(96,96)
        f = xcd + 8 * fi;
        row0 = (q == 2) ? 96 : 0;
        col0 = (q >= 1) ? 96 : 0;
        wq = (q == 1) ? 2 : 1;
    } else {
        int fi = r >> 2, quad = r & 3;
        f = xcd + 8 * fi;
        row0 = (quad >> 1) * 96; col0 = (quad & 1) * 96;
        wq = 1;
    }
    if (f >= NF) return;                // uniform; before any barrier
    const bf16* Xf = X + (size_t)f * FSTRIDE;

    int tid = threadIdx.x;
    int lane = tid & 63, w = tid >> 6;
    int wr = (w >> 1) * 48, wc = (w & 1) * 48;
    int ml = lane & 15, kq = (lane >> 4) * 8;

    f32x4 cr[3][3], ci[3][3];
#pragma unroll
    for (int i = 0; i < 3; ++i)
#pragma unroll
        for (int j = 0; j < 3; ++j) {
            cr[i][j] = f32x4{0.f, 0.f, 0.f, 0.f};
            ci[i][j] = f32x4{0.f, 0.f, 0.f, 0.f};
        }

    for (int kc = 0; kc < CH; kc += 64) {
        i32x4 v[12];
#pragma unroll
        for (int s = 0; s < 4; ++s) {
            const bf16* src = Xf + ((s & 1) ? MAT : 0)
                              + (size_t)((s < 2) ? row0 : col0) * CH + kc;
#pragma unroll
            for (int j = 0; j < 3; ++j) {
                int chunk = j * 256 + tid;
                int rr = chunk >> 3, c8 = chunk & 7;
                v[s * 3 + j] = *(const i32x4*)(src + rr * CH + c8 * 8);
            }
        }
        __syncthreads();
#pragma unroll
        for (int s = 0; s < 4; ++s)
#pragma unroll
            for (int j = 0; j < 3; ++j) {
                int chunk = j * 256 + tid;
                int rr = chunk >> 3, c8 = chunk & 7;
                *(i32x4*)&lds[s * SLAB + rr * LDSR + c8 * 8] = v[s * 3 + j];
            }
        __syncthreads();

#pragma unroll
        for (int ks = 0; ks < 64; ks += 32) {
            bf16x8 ar[3], ai[3], nai[3], br[3], bi[3];
            int ko = ks + kq;
#pragma unroll
            for (int mt = 0; mt < 3; ++mt) {
                ar[mt] = *(const bf16x8*)&lds[0 * SLAB + (wr + mt * 16 + ml) * LDSR + ko];
                ai[mt] = *(const bf16x8*)&lds[1 * SLAB + (wr + mt * 16 + ml) * LDSR + ko];
                br[mt] = *(const bf16x8*)&lds[2 * SLAB + (wc + mt * 16 + ml) * LDSR + ko];
                bi[mt] = *(const bf16x8*)&lds[3 * SLAB + (wc + mt * 16 + ml) * LDSR + ko];
                i32x4 u = __builtin_bit_cast(i32x4, ai[mt]);
                u ^= 0x80008000;   // negate 8 bf16
                nai[mt] = __builtin_bit_cast(bf16x8, u);
            }
#pragma unroll
            for (int mt = 0; mt < 3; ++mt)
#pragma unroll
                for (int nt = 0; nt < 3; ++nt) {
                    cr[mt][nt] = __builtin_amdgcn_mfma_f32_16x16x32_bf16(ar[mt],  br[nt], cr[mt][nt], 0, 0, 0);
                    cr[mt][nt] = __builtin_amdgcn_mfma_f32_16x16x32_bf16(ai[mt],  bi[nt], cr[mt][nt], 0, 0, 0);
                    ci[mt][nt] = __builtin_amdgcn_mfma_f32_16x16x32_bf16(ar[mt],  bi[nt], ci[mt][nt], 0, 0, 0);
                    ci[mt][nt] = __builtin_amdgcn_mfma_f32_16x16x32_bf16(nai[mt], br[nt], ci[mt][nt], 0, 0, 0);
                }
        }
    }

    if (WRITE) {
        // epilogue: frag -> LDS (bf16, b128-aligned tile) -> coalesced b128 stores
        bf16* Yf = Y + (size_t)f * FSTRIDE;
        int lr0 = wr + (lane >> 4) * 4;
        int lc0 = wc + ml;
#pragma unroll
        for (int part = 0; part < 2; ++part) {
            __syncthreads();   // all LDS frag reads (or prev part's stores) done
#pragma unroll
            for (int mt = 0; mt < 3; ++mt)
#pragma unroll
                for (int nt = 0; nt < 3; ++nt)
#pragma unroll
                    for (int rr = 0; rr < 4; ++rr) {
                        float vv = part ? ci[mt][nt][rr] : cr[mt][nt][rr];
                        lds[(lr0 + mt * 16 + rr) * OLDSR + lc0 + nt * 16] = (bf16)vv;
                    }
            __syncthreads();
            bf16* dst = Yf + (part ? MAT : 0) + (size_t)row0 * CH + col0;
            for (int ch = tid; ch < 96 * 12; ch += 256) {
                int rw = ch / 12, cc = ch % 12;
                *(i32x4*)&dst[(size_t)rw * CH + cc * 8] = *(const i32x4*)&lds[rw * OLDSR + cc * 8];
            }
        }
    }
    if (NORM) {
        float loc = 0.f;
#pragma unroll
        for (int mt = 0; mt < 3; ++mt)
#pragma unroll
            for (int nt = 0; nt < 3; ++nt)
#pragma unroll
                for (int rr = 0; rr < 4; ++rr)
                    loc += cr[mt][nt][rr] * cr[mt][nt][rr] + ci[mt][nt][rr] * ci[mt][nt][rr];
#pragma unroll
        for (int off = 32; off > 0; off >>= 1) loc += __shfl_down(loc, off, 64);
        if (lane == 0) red[w] = loc;
        __syncthreads();
        if (tid == 0) {
            float base = (f == 0) ? 1.0f : 2.0f;   // conj-pair weight over freqs
            atomicAdd(s3, base * (float)wq * (red[0] + red[1] + red[2] + red[3]));
        }
    }
}

// sigma = 1024 * (s3/289)^(1/16);  out = K / sigma
__global__ void k_scale(const float* __restrict__ K, float* __restrict__ out,
                        const float* __restrict__ s3) {
    float sig = 1024.0f * exp2f(log2f((*s3) * (1.0f / 289.0f)) * 0.0625f);
    float inv = 1.0f / sig;
    int i = (blockIdx.x * 256 + threadIdx.x) * 4;   // 324 blocks exact
    f32x4 v = *(const f32x4*)(K + i);
    v *= inv;
    *(f32x4*)(out + i) = v;
}

extern "C" void kernel_launch(void* const* d_in, const int* in_sizes, int n_in,
                              void* d_out, int out_size, void* d_ws, size_t ws_size,
                              hipStream_t stream) {
    const float* K = (const float*)d_in[0];
    float* out = (float*)d_out;
    char* ws = (char*)d_ws;
    float* s3 = (float*)ws;
    bf16* bufX = (bf16*)(ws + 256);
    bf16* bufH = bufX + (size_t)NF * FSTRIDE;

    k_dft<<<8 * 5 * 144, 256, 0, stream>>>(K, bufX, s3);                         // X
    k_gram<true,  false><<<8 * 19 * 4, 256, 0, stream>>>(bufX, bufH, nullptr);   // H1
    k_gram<true,  false><<<8 * 19 * 4, 256, 0, stream>>>(bufH, bufX, nullptr);   // H2
    k_gram<false, true ><<<8 * 19 * 3, 256, 0, stream>>>(bufX, nullptr, s3);     // ||H3||^2
    k_scale<<<NELEM / 1024, 256, 0, stream>>>(K, out, s3);
}